// Round 12
// baseline (788.500 us; speedup 1.0000x reference)
//
#include <hip/hip_runtime.h>
#include <hip/hip_bf16.h>

// Problem constants (fixed by setup_inputs)
#define NTOK   2048
#define DIM    256
#define NH     8
#define CH     32
#define QB     4
#define TILE   256
#define TOPK_K 16
#define SCALE  0.17677669529663687f   // 32^-0.5
#define LN_EPS 1e-5f

// p-buffer strides: key contiguous; lq stride 260; head stride 1060
// (1060 % 32 = 4 -> the 8 per-head broadcast b128 reads in the message loop
//  land on disjoint 4-bank groups: h*4 + {0..3} banks, exactly 32 banks)
#define PB_L 260
#define PB_H 1060

// block-wide sum, NT threads (multiple of 64); red[] holds NT/64 floats
template<int NT>
__device__ __forceinline__ float block_sum(float v, float* red){
  #pragma unroll
  for (int off = 32; off > 0; off >>= 1) v += __shfl_xor(v, off, 64);
  const int t = threadIdx.x;
  if ((t & 63) == 0) red[t >> 6] = v;
  __syncthreads();
  float s = 0.f;
  #pragma unroll
  for (int w = 0; w < NT/64; w++) s += red[w];
  __syncthreads();
  return s;
}

// ---------------- K1: LN1 + x @ w_qkv -> Q, KT (transposed), V ----------------
__global__ __launch_bounds__(256) void ln_qkv_kernel(
    const float* __restrict__ point,
    const float* __restrict__ w_qkv,
    const float* __restrict__ c1,     // norm1 w/b pair, order unknown
    const float* __restrict__ c2,
    float* __restrict__ Q,            // [NTOK][DIM]
    float* __restrict__ KT,           // [DIM][NTOK]
    float* __restrict__ V)            // [NTOK][DIM]
{
  __shared__ float xs[4][DIM];
  __shared__ float red[4];
  const int t  = threadIdx.x;
  const int r0 = blockIdx.x * 4;
  const float a1 = c1[t], a2 = c2[t];
  const float s1 = block_sum<256>(fabsf(a1), red);
  const float s2 = block_sum<256>(fabsf(a2), red);
  const float g = (s1 > s2) ? a1 : a2;   // layernorm weight (ones)
  const float b = (s1 > s2) ? a2 : a1;   // layernorm bias  (zeros)
  for (int r = 0; r < 4; r++){
    float v   = point[(r0 + r) * DIM + t];
    float mu  = block_sum<256>(v, red) * (1.f / DIM);
    float d   = v - mu;
    float var = block_sum<256>(d * d, red) * (1.f / DIM);
    xs[r][t]  = d * rsqrtf(var + LN_EPS) * g + b;
  }
  __syncthreads();
  float accq[4] = {}, acck[4] = {}, accv[4] = {};
  for (int d = 0; d < DIM; d++){
    const float w0 = w_qkv[d * 768 + t];
    const float w1 = w_qkv[d * 768 + 256 + t];
    const float w2 = w_qkv[d * 768 + 512 + t];
    #pragma unroll
    for (int r = 0; r < 4; r++){
      const float x = xs[r][d];
      accq[r] = fmaf(x, w0, accq[r]);
      acck[r] = fmaf(x, w1, acck[r]);
      accv[r] = fmaf(x, w2, accv[r]);
    }
  }
  #pragma unroll
  for (int r = 0; r < 4; r++){
    Q[(r0 + r) * DIM + t] = accq[r];
    V[(r0 + r) * DIM + t] = accv[r];
  }
  *(float4*)&KT[(size_t)t * NTOK + r0] =
      make_float4(acck[0], acck[1], acck[2], acck[3]);
}

// ---------------- K2: fused attention + A_mean + streaming top-k ----------------
// 512 threads = 8 waves. Score phase: wave = head, 64 lanes x 4 keys ->
// 256-key tiles, coalesced float4 KT loads. Message phase: wave = key-eighth,
// lane owns dims 4ln..4ln+3. Top-k: per-tile A_mean slice merged into a
// running sorted top-16 (no full 2048-row buffer -> LDS 71->43 KB).
__device__ __forceinline__ void score_tile(
    const float (*qs)[DIM], const float* ktb, int s0, int h, float s[QB][4])
{
  #pragma unroll
  for (int d4 = 0; d4 < 8; d4++){
    const float* kp = ktb + (size_t)(4 * d4) * NTOK + s0;
    const float4 k0 = *(const float4*)(kp);
    const float4 k1 = *(const float4*)(kp + NTOK);
    const float4 k2 = *(const float4*)(kp + 2 * NTOK);
    const float4 k3 = *(const float4*)(kp + 3 * NTOK);
    #pragma unroll
    for (int lq = 0; lq < QB; lq++){
      const float4 q = *(const float4*)&qs[lq][h * CH + 4 * d4];
      s[lq][0] = fmaf(q.x,k0.x, fmaf(q.y,k1.x, fmaf(q.z,k2.x, fmaf(q.w,k3.x, s[lq][0]))));
      s[lq][1] = fmaf(q.x,k0.y, fmaf(q.y,k1.y, fmaf(q.z,k2.y, fmaf(q.w,k3.y, s[lq][1]))));
      s[lq][2] = fmaf(q.x,k0.z, fmaf(q.y,k1.z, fmaf(q.z,k2.z, fmaf(q.w,k3.z, s[lq][2]))));
      s[lq][3] = fmaf(q.x,k0.w, fmaf(q.y,k1.w, fmaf(q.z,k2.w, fmaf(q.w,k3.w, s[lq][3]))));
    }
  }
}

// __launch_bounds__(512, 3): empirical blocks/CU semantics (r8-r11) ->
// 3 blocks x 8 waves = 24 waves/CU, VGPR cap ~85 (demand was 88 at cap 128).
// LDS 42.6 KB x 3 = 128 KB fits.
__global__ __launch_bounds__(512, 3)
void attn_fused_kernel(
    const float* __restrict__ Q,      // [NTOK][DIM]
    const float* __restrict__ KT,     // [DIM][NTOK]
    const float* __restrict__ V,      // [NTOK][DIM]
    float* __restrict__ msg,          // [NTOK][DIM]
    float* __restrict__ out_idx)      // [NTOK][TOPK_K] (indices as f32)
{
  __shared__ float qs[QB][DIM];          // 4 KB (pre-scaled by SCALE)
  __shared__ float pbuf[NH * PB_H];      // 33920 B; overlaid by comb after loop
  __shared__ float amt[QB][TILE];        // 4 KB  (per-tile A_mean slice)
  __shared__ float tv[QB][TOPK_K];       // 256 B (running top-16 values, desc)
  __shared__ int   ti[QB][TOPK_K];       // 256 B (running top-16 indices)
  const int t  = threadIdx.x;
  const int l0 = blockIdx.x * QB;
  const int w  = t >> 6;        // wave id: head (scores) / key-eighth (message)
  const int ln = t & 63;        // lane: 4-key group (scores) / dim-quad (message)
  const int hd = ln >> 3;       // head owning dims 4ln..4ln+3

  for (int i = t; i < QB * DIM; i += 512)
    qs[i >> 8][i & 255] = Q[(l0 + (i >> 8)) * DIM + (i & 255)] * SCALE;
  if (t < QB * TOPK_K){ tv[t >> 4][t & 15] = -1e30f; ti[t >> 4][t & 15] = 0; }
  __syncthreads();

  const float* ktb = KT + (size_t)(w * CH) * NTOK + 4 * ln;

  // ---- phase 1: Z per (lq, head=w). No max subtraction: |s| small, f32-safe.
  float Z[QB] = {0.f, 0.f, 0.f, 0.f};
  for (int s0 = 0; s0 < NTOK; s0 += TILE){
    float s[QB][4] = {};
    score_tile(qs, ktb, s0, w, s);
    #pragma unroll
    for (int lq = 0; lq < QB; lq++)
      Z[lq] += __expf(s[lq][0]) + __expf(s[lq][1])
             + __expf(s[lq][2]) + __expf(s[lq][3]);
  }
  #pragma unroll
  for (int lq = 0; lq < QB; lq++){
    #pragma unroll
    for (int off = 1; off < 64; off <<= 1)
      Z[lq] += __shfl_xor(Z[lq], off, 64);
  }
  float rZ[QB];
  #pragma unroll
  for (int lq = 0; lq < QB; lq++) rZ[lq] = 1.f / Z[lq];

  // ---- phase 2: p -> pbuf; message; A_mean tile; streaming top-k ----
  float4 macc[QB];
  #pragma unroll
  for (int lq = 0; lq < QB; lq++) macc[lq] = make_float4(0.f, 0.f, 0.f, 0.f);

  for (int s0 = 0; s0 < NTOK; s0 += TILE){
    { // (a) scores -> normalized p
      float s[QB][4] = {};
      score_tile(qs, ktb, s0, w, s);
      #pragma unroll
      for (int lq = 0; lq < QB; lq++){
        float4 p;
        p.x = __expf(s[lq][0]) * rZ[lq];
        p.y = __expf(s[lq][1]) * rZ[lq];
        p.z = __expf(s[lq][2]) * rZ[lq];
        p.w = __expf(s[lq][3]) * rZ[lq];
        *(float4*)&pbuf[w * PB_H + lq * PB_L + 4 * ln] = p;
      }
    }
    __syncthreads();
    { // (b) message: wave w -> keys s0+32w..+31; lane ln -> dims 4ln..4ln+3
      const float* vb = V + (size_t)(s0 + w * 32) * DIM + 4 * ln;
      #pragma unroll
      for (int g = 0; g < 8; g++){
        const float4 v0 = *(const float4*)(vb + (4*g + 0) * DIM);
        const float4 v1 = *(const float4*)(vb + (4*g + 1) * DIM);
        const float4 v2 = *(const float4*)(vb + (4*g + 2) * DIM);
        const float4 v3 = *(const float4*)(vb + (4*g + 3) * DIM);
        #pragma unroll
        for (int lq = 0; lq < QB; lq++){
          const float4 p = *(const float4*)&pbuf[hd * PB_H + lq * PB_L + w * 32 + 4 * g];
          macc[lq].x = fmaf(p.x, v0.x, fmaf(p.y, v1.x, fmaf(p.z, v2.x, fmaf(p.w, v3.x, macc[lq].x))));
          macc[lq].y = fmaf(p.x, v0.y, fmaf(p.y, v1.y, fmaf(p.z, v2.y, fmaf(p.w, v3.y, macc[lq].y))));
          macc[lq].z = fmaf(p.x, v0.z, fmaf(p.y, v1.z, fmaf(p.z, v2.z, fmaf(p.w, v3.z, macc[lq].z))));
          macc[lq].w = fmaf(p.x, v0.w, fmaf(p.y, v1.w, fmaf(p.z, v2.w, fmaf(p.w, v3.w, macc[lq].w))));
        }
      }
    }
    { // (c) A_mean tile: 1024 cells, 2 per thread
      #pragma unroll
      for (int rep = 0; rep < 2; rep++){
        const int idx = t + rep * 512;
        const int lq = idx >> 8, key = idx & 255;
        float su = 0.f;
        #pragma unroll
        for (int hh = 0; hh < 8; hh++) su += pbuf[hh * PB_H + lq * PB_L + key];
        amt[lq][key] = su * 0.125f;
      }
    }
    __syncthreads();
    // (d) streaming top-16 merge: wave w<QB owns row w. Stream is in
    // increasing key order; within a tile the argmax prefers lower idx;
    // equal values never displace -> jax.lax.top_k tie semantics preserved.
    if (w < QB){
      const float4 c4 = *(const float4*)&amt[w][4 * ln];
      float cv[4] = {c4.x, c4.y, c4.z, c4.w};
      int   ci[4] = {s0 + 4*ln, s0 + 4*ln + 1, s0 + 4*ln + 2, s0 + 4*ln + 3};
      for (int its = 0; its < TOPK_K; its++){
        float bv = cv[0]; int bi = ci[0];
        #pragma unroll
        for (int c = 1; c < 4; c++)
          if (cv[c] > bv || (cv[c] == bv && ci[c] < bi)){ bv = cv[c]; bi = ci[c]; }
        #pragma unroll
        for (int off = 1; off < 64; off <<= 1){
          const float ov = __shfl_xor(bv, off, 64);
          const int   oi = __shfl_xor(bi, off, 64);
          if (ov > bv || (ov == bv && oi < bi)){ bv = ov; bi = oi; }
        }
        if (!(bv > tv[w][TOPK_K - 1])) break;   // can't displace current min
        if (ln == 0){
          int pos = TOPK_K - 1;
          while (pos > 0 && tv[w][pos - 1] < bv) pos--;
          for (int q = TOPK_K - 1; q > pos; q--){
            tv[w][q] = tv[w][q - 1]; ti[w][q] = ti[w][q - 1];
          }
          tv[w][pos] = bv; ti[w][pos] = bi;
        }
        #pragma unroll
        for (int c = 0; c < 4; c++) if (ci[c] == bi) cv[c] = -1e30f;
      }
    }
    // NOTE: next (a) overwrites pbuf only after the next __syncthreads(),
    // and (d) reads amt which is rewritten only after the barrier following
    // the next (c) -> all waves re-sync at the top of the loop via (a)'s
    // barrier, so (d) is ordered correctly.
  }

  // combine message partials across the 8 key-eighth waves (comb overlays pbuf)
  float* comb = pbuf;   // needs 8*1024 floats = 32768 B <= 33920 B
  #pragma unroll
  for (int lq = 0; lq < QB; lq++)
    *(float4*)&comb[w * (QB * DIM) + lq * DIM + 4 * ln] = macc[lq];
  __syncthreads();
  if (t < 256){
    const int lqo = t >> 6, f4 = (t & 63) * 4;
    float sx = 0.f, sy = 0.f, sz = 0.f, sw = 0.f;
    #pragma unroll
    for (int ww = 0; ww < 8; ww++){
      const float4 r = *(const float4*)&comb[ww * (QB * DIM) + lqo * DIM + f4];
      sx += r.x; sy += r.y; sz += r.z; sw += r.w;
    }
    *(float4*)&msg[(size_t)(l0 + lqo) * DIM + f4] = make_float4(sx, sy, sz, sw);
  }

  // top-16 final write (already sorted desc, ties by lower index)
  if (w < QB && ln < TOPK_K)
    out_idx[(l0 + w) * TOPK_K + ln] = (float)ti[w][ln];
}

// ---------------- K3: msg @ w_proj + b + v residual + LN2 -> out (f32) ----------------
__global__ __launch_bounds__(256) void proj_ln_kernel(
    const float* __restrict__ msg,
    const float* __restrict__ V,
    const float* __restrict__ w_proj,
    const float* __restrict__ b_proj,
    const float* __restrict__ c1,     // norm2 w/b pair, order unknown
    const float* __restrict__ c2,
    float* __restrict__ out)
{
  __shared__ float ms[4][DIM];
  __shared__ float red[4];
  const int t = threadIdx.x, r0 = blockIdx.x * 4;
  const float a1 = c1[t], a2 = c2[t];
  const float s1 = block_sum<256>(fabsf(a1), red);
  const float s2 = block_sum<256>(fabsf(a2), red);
  const float g2 = (s1 > s2) ? a1 : a2;
  const float b2 = (s1 > s2) ? a2 : a1;
  for (int r = 0; r < 4; r++) ms[r][t] = msg[(r0 + r) * DIM + t];
  __syncthreads();
  const float bp = b_proj[t];
  float acc[4] = {bp, bp, bp, bp};
  for (int d = 0; d < DIM; d++){
    const float wv = w_proj[d * DIM + t];
    #pragma unroll
    for (int r = 0; r < 4; r++) acc[r] = fmaf(ms[r][d], wv, acc[r]);
  }
  for (int r = 0; r < 4; r++){
    float a = acc[r] + V[(r0 + r) * DIM + t];   // + v residual
    const float mu  = block_sum<256>(a, red) * (1.f / DIM);
    const float dv  = a - mu;
    const float var = block_sum<256>(dv * dv, red) * (1.f / DIM);
    out[(r0 + r) * DIM + t] = dv * rsqrtf(var + LN_EPS) * g2 + b2;
  }
}

extern "C" void kernel_launch(void* const* d_in, const int* in_sizes, int n_in,
                              void* d_out, int out_size, void* d_ws, size_t ws_size,
                              hipStream_t stream) {
  // Big arrays resolved by unique size (order-proof). Slots: 0=b_proj,
  // 1-2=norm1 pair, 3-4=norm2 pair (w/b disambiguated in-kernel by |sum|).
  const float* point  = nullptr;
  const float* w_qkv  = nullptr;
  const float* w_proj = nullptr;
  const float* v256[5] = {nullptr, nullptr, nullptr, nullptr, nullptr};
  int n256 = 0;
  for (int i = 0; i < n_in; i++){
    const int sz = in_sizes[i];
    if      (sz == NTOK * DIM)      point  = (const float*)d_in[i];
    else if (sz == DIM * 3 * DIM)   w_qkv  = (const float*)d_in[i];
    else if (sz == DIM * DIM)       w_proj = (const float*)d_in[i];
    else if (sz == DIM && n256 < 5) v256[n256++] = (const float*)d_in[i];
  }
  const float* b_proj = v256[0];
  const float* n1a    = v256[1];
  const float* n1c    = v256[2];
  const float* n2a    = v256[3];
  const float* n2c    = v256[4];

  // Output buffer is FLOAT32: [out (2048*256), topk_idx-as-float (2048*16)]
  float* out     = (float*)d_out;
  float* out_idx = out + (size_t)NTOK * DIM;

  // Workspace (8 MB proven safe): Q | KT | V | msg, 2 MB each
  char* ws = (char*)d_ws;
  float* Q   = (float*)(ws);
  float* KT  = (float*)(ws + (size_t)NTOK * DIM * 4);
  float* V   = (float*)(ws + (size_t)NTOK * DIM * 8);
  float* msg = (float*)(ws + (size_t)NTOK * DIM * 12);

  ln_qkv_kernel    <<<NTOK / 4, 256, 0, stream>>>(point, w_qkv, n1a, n1c, Q, KT, V);
  attn_fused_kernel<<<NTOK / 4, 512, 0, stream>>>(Q, KT, V, msg, out_idx);
  proj_ln_kernel   <<<NTOK / 4, 256, 0, stream>>>(msg, V, w_proj, b_proj, n2a, n2c, out);
}

// Round 13
// 583.615 us; speedup vs baseline: 1.3511x; 1.3511x over previous
//
#include <hip/hip_runtime.h>
#include <hip/hip_bf16.h>

// Problem constants (fixed by setup_inputs)
#define NTOK   2048
#define DIM    256
#define NH     8
#define CH     32
#define QB     4
#define TILE   256
#define TOPK_K 16
#define SCALE  0.17677669529663687f   // 32^-0.5
#define LN_EPS 1e-5f

// p-buffer strides: key contiguous; lq stride 260; head stride 1060
// (1060 % 32 = 4 -> the 8 per-head broadcast b128 reads in the message loop
//  land on disjoint 4-bank groups: h*4 + {0..3} banks, exactly 32 banks)
#define PB_L 260
#define PB_H 1060

// block-wide sum, NT threads (multiple of 64); red[] holds NT/64 floats
template<int NT>
__device__ __forceinline__ float block_sum(float v, float* red){
  #pragma unroll
  for (int off = 32; off > 0; off >>= 1) v += __shfl_xor(v, off, 64);
  const int t = threadIdx.x;
  if ((t & 63) == 0) red[t >> 6] = v;
  __syncthreads();
  float s = 0.f;
  #pragma unroll
  for (int w = 0; w < NT/64; w++) s += red[w];
  __syncthreads();
  return s;
}

// ---------------- K1: LN1 + x @ w_qkv -> Q, KT (transposed), V ----------------
__global__ __launch_bounds__(256) void ln_qkv_kernel(
    const float* __restrict__ point,
    const float* __restrict__ w_qkv,
    const float* __restrict__ c1,     // norm1 w/b pair, order unknown
    const float* __restrict__ c2,
    float* __restrict__ Q,            // [NTOK][DIM]
    float* __restrict__ KT,           // [DIM][NTOK]
    float* __restrict__ V)            // [NTOK][DIM]
{
  __shared__ float xs[4][DIM];
  __shared__ float red[4];
  const int t  = threadIdx.x;
  const int r0 = blockIdx.x * 4;
  const float a1 = c1[t], a2 = c2[t];
  const float s1 = block_sum<256>(fabsf(a1), red);
  const float s2 = block_sum<256>(fabsf(a2), red);
  const float g = (s1 > s2) ? a1 : a2;   // layernorm weight (ones)
  const float b = (s1 > s2) ? a2 : a1;   // layernorm bias  (zeros)
  for (int r = 0; r < 4; r++){
    float v   = point[(r0 + r) * DIM + t];
    float mu  = block_sum<256>(v, red) * (1.f / DIM);
    float d   = v - mu;
    float var = block_sum<256>(d * d, red) * (1.f / DIM);
    xs[r][t]  = d * rsqrtf(var + LN_EPS) * g + b;
  }
  __syncthreads();
  float accq[4] = {}, acck[4] = {}, accv[4] = {};
  for (int d = 0; d < DIM; d++){
    const float w0 = w_qkv[d * 768 + t];
    const float w1 = w_qkv[d * 768 + 256 + t];
    const float w2 = w_qkv[d * 768 + 512 + t];
    #pragma unroll
    for (int r = 0; r < 4; r++){
      const float x = xs[r][d];
      accq[r] = fmaf(x, w0, accq[r]);
      acck[r] = fmaf(x, w1, acck[r]);
      accv[r] = fmaf(x, w2, accv[r]);
    }
  }
  #pragma unroll
  for (int r = 0; r < 4; r++){
    Q[(r0 + r) * DIM + t] = accq[r];
    V[(r0 + r) * DIM + t] = accv[r];
  }
  *(float4*)&KT[(size_t)t * NTOK + r0] =
      make_float4(acck[0], acck[1], acck[2], acck[3]);
}

// ---------------- K2: fused attention + A_mean + streaming top-k ----------------
// 512 threads = 8 waves. Score phase: wave = head, 64 lanes x 4 keys ->
// 256-key tiles, coalesced float4 KT loads. Message phase: wave = key-eighth,
// lane owns dims 4ln..4ln+3. Top-k: per-tile A_mean slice merged into a
// running sorted top-16 (LDS-masked candidates, register-light).
__device__ __forceinline__ void score_tile(
    const float (*qs)[DIM], const float* ktb, int s0, int h, float s[QB][4])
{
  #pragma unroll
  for (int d4 = 0; d4 < 8; d4++){
    const float* kp = ktb + (size_t)(4 * d4) * NTOK + s0;
    const float4 k0 = *(const float4*)(kp);
    const float4 k1 = *(const float4*)(kp + NTOK);
    const float4 k2 = *(const float4*)(kp + 2 * NTOK);
    const float4 k3 = *(const float4*)(kp + 3 * NTOK);
    #pragma unroll
    for (int lq = 0; lq < QB; lq++){
      const float4 q = *(const float4*)&qs[lq][h * CH + 4 * d4];
      s[lq][0] = fmaf(q.x,k0.x, fmaf(q.y,k1.x, fmaf(q.z,k2.x, fmaf(q.w,k3.x, s[lq][0]))));
      s[lq][1] = fmaf(q.x,k0.y, fmaf(q.y,k1.y, fmaf(q.z,k2.y, fmaf(q.w,k3.y, s[lq][1]))));
      s[lq][2] = fmaf(q.x,k0.z, fmaf(q.y,k1.z, fmaf(q.z,k2.z, fmaf(q.w,k3.z, s[lq][2]))));
      s[lq][3] = fmaf(q.x,k0.w, fmaf(q.y,k1.w, fmaf(q.z,k2.w, fmaf(q.w,k3.w, s[lq][3]))));
    }
  }
}

// __launch_bounds__(512, 2): min 2 blocks/CU (empirical semantics, r8-r12)
// -> VGPR cap 128. Caps of 85 (r12) and 64 (r9/r10) both forced in-loop
// scratch spills (1.9 GB / 290 MB of HBM spill traffic). NEVER squeeze
// this kernel below ~100 regs.
__global__ __launch_bounds__(512, 2)
void attn_fused_kernel(
    const float* __restrict__ Q,      // [NTOK][DIM]
    const float* __restrict__ KT,     // [DIM][NTOK]
    const float* __restrict__ V,      // [NTOK][DIM]
    float* __restrict__ msg,          // [NTOK][DIM]
    float* __restrict__ out_idx)      // [NTOK][TOPK_K] (indices as f32)
{
  __shared__ float qs[QB][DIM];          // 4 KB (pre-scaled by SCALE)
  __shared__ float pbuf[NH * PB_H];      // 33920 B; overlaid by comb after loop
  __shared__ float amt[QB][TILE];        // 4 KB  (per-tile A_mean slice)
  __shared__ float tv[QB][TOPK_K];       // 256 B (running top-16 values, desc)
  __shared__ int   ti[QB][TOPK_K];       // 256 B (running top-16 indices)
  const int t  = threadIdx.x;
  const int l0 = blockIdx.x * QB;
  const int w  = t >> 6;        // wave id: head (scores) / key-eighth (message)
  const int ln = t & 63;        // lane: 4-key group (scores) / dim-quad (message)
  const int hd = ln >> 3;       // head owning dims 4ln..4ln+3

  for (int i = t; i < QB * DIM; i += 512)
    qs[i >> 8][i & 255] = Q[(l0 + (i >> 8)) * DIM + (i & 255)] * SCALE;
  if (t < QB * TOPK_K){ tv[t >> 4][t & 15] = -1e30f; ti[t >> 4][t & 15] = 0; }
  __syncthreads();

  const float* ktb = KT + (size_t)(w * CH) * NTOK + 4 * ln;

  // ---- phase 1: Z per (lq, head=w). No max subtraction: |s| small, f32-safe.
  float Z[QB] = {0.f, 0.f, 0.f, 0.f};
  for (int s0 = 0; s0 < NTOK; s0 += TILE){
    float s[QB][4] = {};
    score_tile(qs, ktb, s0, w, s);
    #pragma unroll
    for (int lq = 0; lq < QB; lq++)
      Z[lq] += __expf(s[lq][0]) + __expf(s[lq][1])
             + __expf(s[lq][2]) + __expf(s[lq][3]);
  }
  #pragma unroll
  for (int lq = 0; lq < QB; lq++){
    #pragma unroll
    for (int off = 1; off < 64; off <<= 1)
      Z[lq] += __shfl_xor(Z[lq], off, 64);
  }
  float rZ[QB];
  #pragma unroll
  for (int lq = 0; lq < QB; lq++) rZ[lq] = 1.f / Z[lq];

  // ---- phase 2: p -> pbuf; message; A_mean tile; streaming top-k ----
  float4 macc[QB];
  #pragma unroll
  for (int lq = 0; lq < QB; lq++) macc[lq] = make_float4(0.f, 0.f, 0.f, 0.f);

  for (int s0 = 0; s0 < NTOK; s0 += TILE){
    { // (a) scores -> normalized p
      float s[QB][4] = {};
      score_tile(qs, ktb, s0, w, s);
      #pragma unroll
      for (int lq = 0; lq < QB; lq++){
        float4 p;
        p.x = __expf(s[lq][0]) * rZ[lq];
        p.y = __expf(s[lq][1]) * rZ[lq];
        p.z = __expf(s[lq][2]) * rZ[lq];
        p.w = __expf(s[lq][3]) * rZ[lq];
        *(float4*)&pbuf[w * PB_H + lq * PB_L + 4 * ln] = p;
      }
    }
    __syncthreads();
    { // (b) message: wave w -> keys s0+32w..+31; lane ln -> dims 4ln..4ln+3
      const float* vb = V + (size_t)(s0 + w * 32) * DIM + 4 * ln;
      #pragma unroll
      for (int g = 0; g < 8; g++){
        const float4 v0 = *(const float4*)(vb + (4*g + 0) * DIM);
        const float4 v1 = *(const float4*)(vb + (4*g + 1) * DIM);
        const float4 v2 = *(const float4*)(vb + (4*g + 2) * DIM);
        const float4 v3 = *(const float4*)(vb + (4*g + 3) * DIM);
        #pragma unroll
        for (int lq = 0; lq < QB; lq++){
          const float4 p = *(const float4*)&pbuf[hd * PB_H + lq * PB_L + w * 32 + 4 * g];
          macc[lq].x = fmaf(p.x, v0.x, fmaf(p.y, v1.x, fmaf(p.z, v2.x, fmaf(p.w, v3.x, macc[lq].x))));
          macc[lq].y = fmaf(p.x, v0.y, fmaf(p.y, v1.y, fmaf(p.z, v2.y, fmaf(p.w, v3.y, macc[lq].y))));
          macc[lq].z = fmaf(p.x, v0.z, fmaf(p.y, v1.z, fmaf(p.z, v2.z, fmaf(p.w, v3.z, macc[lq].z))));
          macc[lq].w = fmaf(p.x, v0.w, fmaf(p.y, v1.w, fmaf(p.z, v2.w, fmaf(p.w, v3.w, macc[lq].w))));
        }
      }
    }
    { // (c) A_mean tile: 1024 cells, 2 per thread
      #pragma unroll
      for (int rep = 0; rep < 2; rep++){
        const int idx = t + rep * 512;
        const int lq = idx >> 8, key = idx & 255;
        float su = 0.f;
        #pragma unroll
        for (int hh = 0; hh < 8; hh++) su += pbuf[hh * PB_H + lq * PB_L + key];
        amt[lq][key] = su * 0.125f;
      }
    }
    __syncthreads();
    // (d) streaming top-16 merge: wave w<QB owns row w. Candidates re-read
    // from amt each iteration (register-light); taken entries masked in LDS.
    // Stream is in increasing index order; equal values never displace ->
    // jax.lax.top_k tie semantics preserved.
    if (w < QB){
      for (int its = 0; its < TOPK_K; its++){
        const float4 c4 = *(const float4*)&amt[w][4 * ln];
        float bv = c4.x; int bi = 4 * ln;
        if (c4.y > bv){ bv = c4.y; bi = 4 * ln + 1; }
        if (c4.z > bv){ bv = c4.z; bi = 4 * ln + 2; }
        if (c4.w > bv){ bv = c4.w; bi = 4 * ln + 3; }
        #pragma unroll
        for (int off = 1; off < 64; off <<= 1){
          const float ov = __shfl_xor(bv, off, 64);
          const int   oi = __shfl_xor(bi, off, 64);
          if (ov > bv || (ov == bv && oi < bi)){ bv = ov; bi = oi; }
        }
        if (!(bv > tv[w][TOPK_K - 1])) break;   // can't displace current min
        if (ln == 0){
          int pos = TOPK_K - 1;
          while (pos > 0 && tv[w][pos - 1] < bv) pos--;
          for (int q = TOPK_K - 1; q > pos; q--){
            tv[w][q] = tv[w][q - 1]; ti[w][q] = ti[w][q - 1];
          }
          tv[w][pos] = bv; ti[w][pos] = s0 + bi;
          amt[w][bi] = -1e30f;   // mask; same-wave DS order -> visible next iter
        }
      }
    }
    // Ordering: waves 4-7 skip (d) and wait at (a)'s barrier next iteration;
    // (c) (which rewrites amt) only runs after that barrier, i.e. after all
    // (d) readers finished. pbuf likewise only rewritten after the barrier.
  }

  // combine message partials across the 8 key-eighth waves (comb overlays pbuf)
  float* comb = pbuf;   // needs 8*1024 floats = 32768 B <= 33920 B
  #pragma unroll
  for (int lq = 0; lq < QB; lq++)
    *(float4*)&comb[w * (QB * DIM) + lq * DIM + 4 * ln] = macc[lq];
  __syncthreads();
  if (t < 256){
    const int lqo = t >> 6, f4 = (t & 63) * 4;
    float sx = 0.f, sy = 0.f, sz = 0.f, sw = 0.f;
    #pragma unroll
    for (int ww = 0; ww < 8; ww++){
      const float4 r = *(const float4*)&comb[ww * (QB * DIM) + lqo * DIM + f4];
      sx += r.x; sy += r.y; sz += r.z; sw += r.w;
    }
    *(float4*)&msg[(size_t)(l0 + lqo) * DIM + f4] = make_float4(sx, sy, sz, sw);
  }

  // top-16 final write (already sorted desc, ties by lower index)
  if (w < QB && ln < TOPK_K)
    out_idx[(l0 + w) * TOPK_K + ln] = (float)ti[w][ln];
}

// ---------------- K3: msg @ w_proj + b + v residual + LN2 -> out (f32) ----------------
__global__ __launch_bounds__(256) void proj_ln_kernel(
    const float* __restrict__ msg,
    const float* __restrict__ V,
    const float* __restrict__ w_proj,
    const float* __restrict__ b_proj,
    const float* __restrict__ c1,     // norm2 w/b pair, order unknown
    const float* __restrict__ c2,
    float* __restrict__ out)
{
  __shared__ float ms[4][DIM];
  __shared__ float red[4];
  const int t = threadIdx.x, r0 = blockIdx.x * 4;
  const float a1 = c1[t], a2 = c2[t];
  const float s1 = block_sum<256>(fabsf(a1), red);
  const float s2 = block_sum<256>(fabsf(a2), red);
  const float g2 = (s1 > s2) ? a1 : a2;
  const float b2 = (s1 > s2) ? a2 : a1;
  for (int r = 0; r < 4; r++) ms[r][t] = msg[(r0 + r) * DIM + t];
  __syncthreads();
  const float bp = b_proj[t];
  float acc[4] = {bp, bp, bp, bp};
  for (int d = 0; d < DIM; d++){
    const float wv = w_proj[d * DIM + t];
    #pragma unroll
    for (int r = 0; r < 4; r++) acc[r] = fmaf(ms[r][d], wv, acc[r]);
  }
  for (int r = 0; r < 4; r++){
    float a = acc[r] + V[(r0 + r) * DIM + t];   // + v residual
    const float mu  = block_sum<256>(a, red) * (1.f / DIM);
    const float dv  = a - mu;
    const float var = block_sum<256>(dv * dv, red) * (1.f / DIM);
    out[(r0 + r) * DIM + t] = dv * rsqrtf(var + LN_EPS) * g2 + b2;
  }
}

extern "C" void kernel_launch(void* const* d_in, const int* in_sizes, int n_in,
                              void* d_out, int out_size, void* d_ws, size_t ws_size,
                              hipStream_t stream) {
  // Big arrays resolved by unique size (order-proof). Slots: 0=b_proj,
  // 1-2=norm1 pair, 3-4=norm2 pair (w/b disambiguated in-kernel by |sum|).
  const float* point  = nullptr;
  const float* w_qkv  = nullptr;
  const float* w_proj = nullptr;
  const float* v256[5] = {nullptr, nullptr, nullptr, nullptr, nullptr};
  int n256 = 0;
  for (int i = 0; i < n_in; i++){
    const int sz = in_sizes[i];
    if      (sz == NTOK * DIM)      point  = (const float*)d_in[i];
    else if (sz == DIM * 3 * DIM)   w_qkv  = (const float*)d_in[i];
    else if (sz == DIM * DIM)       w_proj = (const float*)d_in[i];
    else if (sz == DIM && n256 < 5) v256[n256++] = (const float*)d_in[i];
  }
  const float* b_proj = v256[0];
  const float* n1a    = v256[1];
  const float* n1c    = v256[2];
  const float* n2a    = v256[3];
  const float* n2c    = v256[4];

  // Output buffer is FLOAT32: [out (2048*256), topk_idx-as-float (2048*16)]
  float* out     = (float*)d_out;
  float* out_idx = out + (size_t)NTOK * DIM;

  // Workspace (8 MB proven safe): Q | KT | V | msg, 2 MB each
  char* ws = (char*)d_ws;
  float* Q   = (float*)(ws);
  float* KT  = (float*)(ws + (size_t)NTOK * DIM * 4);
  float* V   = (float*)(ws + (size_t)NTOK * DIM * 8);
  float* msg = (float*)(ws + (size_t)NTOK * DIM * 12);

  ln_qkv_kernel    <<<NTOK / 4, 256, 0, stream>>>(point, w_qkv, n1a, n1c, Q, KT, V);
  attn_fused_kernel<<<NTOK / 4, 512, 0, stream>>>(Q, KT, V, msg, out_idx);
  proj_ln_kernel   <<<NTOK / 4, 256, 0, stream>>>(msg, V, w_proj, b_proj, n2a, n2c, out);
}

// Round 14
// 388.666 us; speedup vs baseline: 2.0287x; 1.5016x over previous
//
#include <hip/hip_runtime.h>
#include <hip/hip_bf16.h>

// Problem constants (fixed by setup_inputs)
#define NTOK   2048
#define DIM    256
#define NH     8
#define CH     32
#define QB     4
#define TILE   128
#define TOPK_K 16
#define SCALE  0.17677669529663687f   // 32^-0.5
#define LN_EPS 1e-5f

// p-buffer strides (128-key tile): key contiguous; lq stride 132; head
// stride 532 (532%32=20 -> per-head broadcast b128 reads land on disjoint
// bank groups; measured 0 conflicts with this layout in r7/r8).
#define PB_L 132
#define PB_H 532

// block-wide sum, NT threads (multiple of 64); red[] holds NT/64 floats
template<int NT>
__device__ __forceinline__ float block_sum(float v, float* red){
  #pragma unroll
  for (int off = 32; off > 0; off >>= 1) v += __shfl_xor(v, off, 64);
  const int t = threadIdx.x;
  if ((t & 63) == 0) red[t >> 6] = v;
  __syncthreads();
  float s = 0.f;
  #pragma unroll
  for (int w = 0; w < NT/64; w++) s += red[w];
  __syncthreads();
  return s;
}

// ---------------- K1: LN1 + x @ w_qkv -> Q, KT (transposed), V ----------------
__global__ __launch_bounds__(256) void ln_qkv_kernel(
    const float* __restrict__ point,
    const float* __restrict__ w_qkv,
    const float* __restrict__ c1,     // norm1 w/b pair, order unknown
    const float* __restrict__ c2,
    float* __restrict__ Q,            // [NTOK][DIM]
    float* __restrict__ KT,           // [DIM][NTOK]
    float* __restrict__ V)            // [NTOK][DIM]
{
  __shared__ float xs[4][DIM];
  __shared__ float red[4];
  const int t  = threadIdx.x;
  const int r0 = blockIdx.x * 4;
  const float a1 = c1[t], a2 = c2[t];
  const float s1 = block_sum<256>(fabsf(a1), red);
  const float s2 = block_sum<256>(fabsf(a2), red);
  const float g = (s1 > s2) ? a1 : a2;   // layernorm weight (ones)
  const float b = (s1 > s2) ? a2 : a1;   // layernorm bias  (zeros)
  for (int r = 0; r < 4; r++){
    float v   = point[(r0 + r) * DIM + t];
    float mu  = block_sum<256>(v, red) * (1.f / DIM);
    float d   = v - mu;
    float var = block_sum<256>(d * d, red) * (1.f / DIM);
    xs[r][t]  = d * rsqrtf(var + LN_EPS) * g + b;
  }
  __syncthreads();
  float accq[4] = {}, acck[4] = {}, accv[4] = {};
  for (int d = 0; d < DIM; d++){
    const float w0 = w_qkv[d * 768 + t];
    const float w1 = w_qkv[d * 768 + 256 + t];
    const float w2 = w_qkv[d * 768 + 512 + t];
    #pragma unroll
    for (int r = 0; r < 4; r++){
      const float x = xs[r][d];
      accq[r] = fmaf(x, w0, accq[r]);
      acck[r] = fmaf(x, w1, acck[r]);
      accv[r] = fmaf(x, w2, accv[r]);
    }
  }
  #pragma unroll
  for (int r = 0; r < 4; r++){
    Q[(r0 + r) * DIM + t] = accq[r];
    V[(r0 + r) * DIM + t] = accv[r];
  }
  *(float4*)&KT[(size_t)t * NTOK + r0] =
      make_float4(acck[0], acck[1], acck[2], acck[3]);
}

// ---------------- K2: fused attention + A_mean + top-k ----------------
// 512 threads = 8 waves. Score phase: wave = head, 64 lanes x 2 keys ->
// 128-key tiles, coalesced float2 KT loads. Message phase: wave = key
// sixteenth (16 keys), lane owns dims 4ln..4ln+3. Top-k after the loop on
// the full am[] row (r11 structure: measured 88 VGPR, no spill).
__device__ __forceinline__ void score_tile(
    const float (*qs)[DIM], const float* ktb, int s0, int h, float s[QB][2])
{
  #pragma unroll
  for (int d4 = 0; d4 < 8; d4++){
    const float* kp = ktb + (size_t)(4 * d4) * NTOK + s0;
    const float2 k0 = *(const float2*)(kp);
    const float2 k1 = *(const float2*)(kp + NTOK);
    const float2 k2 = *(const float2*)(kp + 2 * NTOK);
    const float2 k3 = *(const float2*)(kp + 3 * NTOK);
    #pragma unroll
    for (int lq = 0; lq < QB; lq++){
      const float4 q = *(const float4*)&qs[lq][h * CH + 4 * d4];
      s[lq][0] = fmaf(q.x,k0.x, fmaf(q.y,k1.x, fmaf(q.z,k2.x, fmaf(q.w,k3.x, s[lq][0]))));
      s[lq][1] = fmaf(q.x,k0.y, fmaf(q.y,k1.y, fmaf(q.z,k2.y, fmaf(q.w,k3.y, s[lq][1]))));
    }
  }
}

// (512,2): min 2 blocks/CU -> VGPR cap 128. Demand (r11 structure) ~88.
// Caps below ~100 spill this kernel (r9/r10/r12/r13 evidence).
__global__ __launch_bounds__(512, 2)
void attn_fused_kernel(
    const float* __restrict__ Q,      // [NTOK][DIM]
    const float* __restrict__ KT,     // [DIM][NTOK]
    const float* __restrict__ V,      // [NTOK][DIM]
    float* __restrict__ msg,          // [NTOK][DIM]
    float* __restrict__ out_idx)      // [NTOK][TOPK_K] (indices as f32)
{
  __shared__ float qs[QB][DIM];          // 4 KB (pre-scaled by SCALE)
  __shared__ float pbuf[NH * PB_H];      // 17024 B; comb overlays after loop
  __shared__ float am[QB][NTOK];         // 32 KB
  const int t  = threadIdx.x;
  const int l0 = blockIdx.x * QB;
  const int w  = t >> 6;        // wave id: head (scores) / key-16th (message)
  const int ln = t & 63;        // lane: 2-key group (scores) / dim-quad (message)
  const int hd = ln >> 3;       // head owning dims 4ln..4ln+3

  for (int i = t; i < QB * DIM; i += 512)
    qs[i >> 8][i & 255] = Q[(l0 + (i >> 8)) * DIM + (i & 255)] * SCALE;
  __syncthreads();

  const float* ktb = KT + (size_t)(w * CH) * NTOK + 2 * ln;

  // ---- phase 1: Z per (lq, head=w). No max subtraction: |s| small, f32-safe.
  float Z[QB] = {0.f, 0.f, 0.f, 0.f};
  for (int s0 = 0; s0 < NTOK; s0 += TILE){
    float s[QB][2] = {};
    score_tile(qs, ktb, s0, w, s);
    #pragma unroll
    for (int lq = 0; lq < QB; lq++)
      Z[lq] += __expf(s[lq][0]) + __expf(s[lq][1]);
  }
  #pragma unroll
  for (int lq = 0; lq < QB; lq++){
    #pragma unroll
    for (int off = 1; off < 64; off <<= 1)
      Z[lq] += __shfl_xor(Z[lq], off, 64);
  }
  float rZ[QB];
  #pragma unroll
  for (int lq = 0; lq < QB; lq++) rZ[lq] = 1.f / Z[lq];

  // ---- phase 2: p -> pbuf; message; A_mean row ----
  float4 macc[QB];
  #pragma unroll
  for (int lq = 0; lq < QB; lq++) macc[lq] = make_float4(0.f, 0.f, 0.f, 0.f);

  for (int s0 = 0; s0 < NTOK; s0 += TILE){
    { // (a) scores -> normalized p
      float s[QB][2] = {};
      score_tile(qs, ktb, s0, w, s);
      #pragma unroll
      for (int lq = 0; lq < QB; lq++){
        float2 p;
        p.x = __expf(s[lq][0]) * rZ[lq];
        p.y = __expf(s[lq][1]) * rZ[lq];
        *(float2*)&pbuf[w * PB_H + lq * PB_L + 2 * ln] = p;
      }
    }
    __syncthreads();
    { // (b) message: wave w -> keys s0+16w..+15; lane ln -> dims 4ln..4ln+3
      const float* vb = V + (size_t)(s0 + w * 16) * DIM + 4 * ln;
      #pragma unroll
      for (int g = 0; g < 4; g++){
        const float4 v0 = *(const float4*)(vb + (4*g + 0) * DIM);
        const float4 v1 = *(const float4*)(vb + (4*g + 1) * DIM);
        const float4 v2 = *(const float4*)(vb + (4*g + 2) * DIM);
        const float4 v3 = *(const float4*)(vb + (4*g + 3) * DIM);
        #pragma unroll
        for (int lq = 0; lq < QB; lq++){
          const float4 p = *(const float4*)&pbuf[hd * PB_H + lq * PB_L + w * 16 + 4 * g];
          macc[lq].x = fmaf(p.x, v0.x, fmaf(p.y, v1.x, fmaf(p.z, v2.x, fmaf(p.w, v3.x, macc[lq].x))));
          macc[lq].y = fmaf(p.x, v0.y, fmaf(p.y, v1.y, fmaf(p.z, v2.y, fmaf(p.w, v3.y, macc[lq].y))));
          macc[lq].z = fmaf(p.x, v0.z, fmaf(p.y, v1.z, fmaf(p.z, v2.z, fmaf(p.w, v3.z, macc[lq].z))));
          macc[lq].w = fmaf(p.x, v0.w, fmaf(p.y, v1.w, fmaf(p.z, v2.w, fmaf(p.w, v3.w, macc[lq].w))));
        }
      }
    }
    { // (c) A_mean: 512 cells, 1 per thread
      const int lq = t >> 7, key = t & 127;
      float su = 0.f;
      #pragma unroll
      for (int hh = 0; hh < 8; hh++) su += pbuf[hh * PB_H + lq * PB_L + key];
      am[lq][s0 + key] = su * 0.125f;
    }
    __syncthreads();
  }

  // ---- message combine across 8 waves, two staged halves (comb = pbuf) ----
  float* comb = pbuf;   // needs 4*1024 floats = 16384 B <= 17024 B
  if (w < 4){
    #pragma unroll
    for (int lq = 0; lq < QB; lq++)
      *(float4*)&comb[w * 1024 + lq * 256 + 4 * ln] = macc[lq];
  }
  __syncthreads();
  float mx = 0.f, my = 0.f;
  {
    const int c = 2 * t;
    #pragma unroll
    for (int ww = 0; ww < 4; ww++){
      const float2 r = *(const float2*)&comb[ww * 1024 + c];
      mx += r.x; my += r.y;
    }
  }
  __syncthreads();
  if (w >= 4){
    #pragma unroll
    for (int lq = 0; lq < QB; lq++)
      *(float4*)&comb[(w - 4) * 1024 + lq * 256 + 4 * ln] = macc[lq];
  }
  __syncthreads();
  {
    const int c = 2 * t;
    #pragma unroll
    for (int ww = 0; ww < 4; ww++){
      const float2 r = *(const float2*)&comb[ww * 1024 + c];
      mx += r.x; my += r.y;
    }
    const int lq = c >> 8, d = c & 255;
    *(float2*)&msg[(size_t)(l0 + lq) * DIM + d] = make_float2(mx, my);
  }

  // ---- top-k per row: wave r<QB owns am[r] (r11 structure) ----
  if (w < QB){
    for (int it = 0; it < TOPK_K; it++){
      float bv = -1e30f; int bi = 0x7fffffff;
      #pragma unroll
      for (int b = 0; b < NTOK / 64; b++){
        const int idx = b * 64 + ln;
        const float v = am[w][idx];
        if (v > bv || (v == bv && idx < bi)){ bv = v; bi = idx; }
      }
      #pragma unroll
      for (int off = 1; off < 64; off <<= 1){
        const float ov = __shfl_xor(bv, off, 64);
        const int   oi = __shfl_xor(bi, off, 64);
        if (ov > bv || (ov == bv && oi < bi)){ bv = ov; bi = oi; }
      }
      if (ln == 0){
        out_idx[(l0 + w) * TOPK_K + it] = (float)bi;
        am[w][bi] = -1e30f;   // same-wave DS ordering: visible next iteration
      }
    }
  }
}

// ---------------- K3: msg @ w_proj + b + v residual + LN2 -> out (f32) ----------------
__global__ __launch_bounds__(256) void proj_ln_kernel(
    const float* __restrict__ msg,
    const float* __restrict__ V,
    const float* __restrict__ w_proj,
    const float* __restrict__ b_proj,
    const float* __restrict__ c1,     // norm2 w/b pair, order unknown
    const float* __restrict__ c2,
    float* __restrict__ out)
{
  __shared__ float ms[4][DIM];
  __shared__ float red[4];
  const int t = threadIdx.x, r0 = blockIdx.x * 4;
  const float a1 = c1[t], a2 = c2[t];
  const float s1 = block_sum<256>(fabsf(a1), red);
  const float s2 = block_sum<256>(fabsf(a2), red);
  const float g2 = (s1 > s2) ? a1 : a2;
  const float b2 = (s1 > s2) ? a2 : a1;
  for (int r = 0; r < 4; r++) ms[r][t] = msg[(r0 + r) * DIM + t];
  __syncthreads();
  const float bp = b_proj[t];
  float acc[4] = {bp, bp, bp, bp};
  for (int d = 0; d < DIM; d++){
    const float wv = w_proj[d * DIM + t];
    #pragma unroll
    for (int r = 0; r < 4; r++) acc[r] = fmaf(ms[r][d], wv, acc[r]);
  }
  for (int r = 0; r < 4; r++){
    float a = acc[r] + V[(r0 + r) * DIM + t];   // + v residual
    const float mu  = block_sum<256>(a, red) * (1.f / DIM);
    const float dv  = a - mu;
    const float var = block_sum<256>(dv * dv, red) * (1.f / DIM);
    out[(r0 + r) * DIM + t] = dv * rsqrtf(var + LN_EPS) * g2 + b2;
  }
}

extern "C" void kernel_launch(void* const* d_in, const int* in_sizes, int n_in,
                              void* d_out, int out_size, void* d_ws, size_t ws_size,
                              hipStream_t stream) {
  // Big arrays resolved by unique size (order-proof). Slots: 0=b_proj,
  // 1-2=norm1 pair, 3-4=norm2 pair (w/b disambiguated in-kernel by |sum|).
  const float* point  = nullptr;
  const float* w_qkv  = nullptr;
  const float* w_proj = nullptr;
  const float* v256[5] = {nullptr, nullptr, nullptr, nullptr, nullptr};
  int n256 = 0;
  for (int i = 0; i < n_in; i++){
    const int sz = in_sizes[i];
    if      (sz == NTOK * DIM)      point  = (const float*)d_in[i];
    else if (sz == DIM * 3 * DIM)   w_qkv  = (const float*)d_in[i];
    else if (sz == DIM * DIM)       w_proj = (const float*)d_in[i];
    else if (sz == DIM && n256 < 5) v256[n256++] = (const float*)d_in[i];
  }
  const float* b_proj = v256[0];
  const float* n1a    = v256[1];
  const float* n1c    = v256[2];
  const float* n2a    = v256[3];
  const float* n2c    = v256[4];

  // Output buffer is FLOAT32: [out (2048*256), topk_idx-as-float (2048*16)]
  float* out     = (float*)d_out;
  float* out_idx = out + (size_t)NTOK * DIM;

  // Workspace (8 MB proven safe): Q | KT | V | msg, 2 MB each
  char* ws = (char*)d_ws;
  float* Q   = (float*)(ws);
  float* KT  = (float*)(ws + (size_t)NTOK * DIM * 4);
  float* V   = (float*)(ws + (size_t)NTOK * DIM * 8);
  float* msg = (float*)(ws + (size_t)NTOK * DIM * 12);

  ln_qkv_kernel    <<<NTOK / 4, 256, 0, stream>>>(point, w_qkv, n1a, n1c, Q, KT, V);
  attn_fused_kernel<<<NTOK / 4, 512, 0, stream>>>(Q, KT, V, msg, out_idx);
  proj_ln_kernel   <<<NTOK / 4, 256, 0, stream>>>(msg, V, w_proj, b_proj, n2a, n2c, out);
}